// Round 2
// baseline (4501.798 us; speedup 1.0000x reference)
//
#include <hip/hip_runtime.h>
#include <hip/hip_bf16.h>

#define B_ 64
#define T_ 512
#define D_ 512
#define H_ 1024
#define G_ 4096
#define NJ 16              // j-columns per wg
#define WGS 128            // 1 wg/CU on half the chip (latency-bound)
#define APE 520            // A-chunk row stride in u16 (1040 B = 1024 + 16 pad)
#define ABUF_B (64 * APE * 2)          // 66560 B per A chunk buffer
#define CLP 67                         // C tile row stride (floats)
#define LDS_TOTAL (2 * ABUF_B)         // 133120 B ; Cl[2][64][CLP] overlays Ab0

typedef unsigned short u16;
typedef __bf16 v8bf __attribute__((ext_vector_type(8)));
typedef unsigned short v8us __attribute__((ext_vector_type(8)));
typedef float v4f __attribute__((ext_vector_type(4)));

#define MFMA(a, b, c) __builtin_amdgcn_mfma_f32_16x16x32_bf16(a, b, c, 0, 0, 0)

__device__ __forceinline__ u16 f2bf(float f) {
    unsigned u = __builtin_bit_cast(unsigned, f);
    u += 0x7fffu + ((u >> 16) & 1u);   // RNE
    return (u16)(u >> 16);
}
__device__ __forceinline__ u16 f2h(float f) {
    _Float16 h = (_Float16)f;
    return __builtin_bit_cast(u16, h);
}
__device__ __forceinline__ float f16lo(unsigned w) {
    return (float)__builtin_bit_cast(_Float16, (u16)(w & 0xffffu));
}
__device__ __forceinline__ float f16hi(unsigned w) {
    return (float)__builtin_bit_cast(_Float16, (u16)(w >> 16));
}
__device__ __forceinline__ float sigm(float x) { return 1.0f / (1.0f + __expf(-x)); }
__device__ __forceinline__ float tanh_f(float x) { return 1.0f - 2.0f / (__expf(2.0f * x) + 1.0f); }

// async global->LDS, 16B/lane; lds dst wave-uniform base (lane*16 implicit)
__device__ __forceinline__ void gl_lds(const u16* g, u16* l) {
    __builtin_amdgcn_global_load_lds(
        (const __attribute__((address_space(1))) unsigned int*)g,
        (__attribute__((address_space(3))) unsigned int*)l, 16, 0, 0);
}
// device-coherent variant: cpol 17 = sc0 sc1 (read at LLC coherence point)
__device__ __forceinline__ void gl_lds_c(const u16* g, u16* l) {
    __builtin_amdgcn_global_load_lds(
        (const __attribute__((address_space(1))) unsigned int*)g,
        (__attribute__((address_space(3))) unsigned int*)l, 16, 0, 17);
}

// ---------------- pre-pass: x -> [T,B,D] bf16, zero h0 + flags ----------------
__global__ void prep_kernel(const float* __restrict__ xin, u16* __restrict__ xT,
                            u16* __restrict__ hb, int* __restrict__ gen) {
    int gid = blockIdx.x * 256 + threadIdx.x;           // over B*T*(D/4) = 4.19M
    if (gid < 65536) ((unsigned int*)hb)[gid] = 0u;     // parity-0 h buffers (256 KB)
    if (gid < 256) gen[gid] = 0;                        // step flags [0..127] + done flags [128..255]
    int d0 = (gid & 127) * 4;
    int bt = gid >> 7;
    int b = bt >> 9, t = bt & 511;
    float4 v = *(const float4*)(xin + (size_t)bt * D_ + d0);
    ushort4 o;
    o.x = f2bf(v.x); o.y = f2bf(v.y); o.z = f2bf(v.z); o.w = f2bf(v.w);
    *(ushort4*)(xT + ((size_t)t * B_ + b) * D_ + d0) = o;
}

// ---------------- persistent kernel: phase 0 (xz precompute) + scan ----------------
// 128 wgs x 512 threads (8 waves), 1 wg/CU, 2 waves/SIMD.
// Phase 0: wg (widp=wg>>1, th=wg&1) computes xz[dirp][widp][t in th-half] for both dirs.
//   waves (mq=w>>1: 16-row quarter, nh=w&1: 2-gate pair), K=512 full, bias folded into acc.
//   xz stored f16 (plain cached) -> one-time wbl2 + done-flag grid sync.
// Scan: wg (dir=wg&1, wid=wg>>1). waves (kh=w&1: K-half of h, np=(w>>1)&1: 2-gate pair,
//   mh=w>>2: 32-row half). Wh frags in regs (32 x v8bf = 128 regs). K=1024 (h only).
//   Cl[2][64][CLP] f32 partials overlay Ab0 (safe: written after b3, consumed before b5).
extern "C" __global__ void __launch_bounds__(512, 2)
scan_kernel(const float* __restrict__ Wx_f, const float* __restrict__ Wh_f,
            const float* __restrict__ b_f,
            const float* __restrict__ Wx_b, const float* __restrict__ Wh_b,
            const float* __restrict__ b_b,
            const u16* __restrict__ xT, u16* __restrict__ hb,
            int* __restrict__ gen, u16* __restrict__ xz,
            float* __restrict__ out) {
    extern __shared__ char smem[];
    u16* Ab0 = (u16*)smem;
    u16* Ab1 = (u16*)(smem + ABUF_B);
    float* Cl = (float*)smem;              // [2][64][CLP] f32, overlays Ab0

    const int tid = threadIdx.x;
    const int wg  = blockIdx.x;
    const int w    = tid >> 6;
    const int lane = tid & 63;
    const int quad = lane >> 4;
    const int l15  = lane & 15;
    const int srow = w * 8;                 // staging rows w*8..w*8+7
    const int loff = lane * 8;              // 16B per lane

    v8bf bfr[32];

    auto stageX = [&](int t, u16* buf) {
        const u16* src = xT + (size_t)t * (B_ * D_);
        #pragma unroll
        for (int r = 0; r < 8; ++r)
            gl_lds(src + (srow + r) * D_ + loff, buf + (srow + r) * APE);
    };

    // ================= PHASE 0: xz = x @ Wx + bias (f16) =================
    {
        const int widp = wg >> 1;
        const int th   = wg & 1;
        const int j0p  = widp * NJ;
        const int mq = w >> 1;              // 0..3 (16-row quarter)
        const int nh = w & 1;               // gate pair
        const int arp = (mq * 16 + l15) * APE + quad * 8;

        for (int dirp = 0; dirp < 2; ++dirp) {
            const float* WxP = dirp ? Wx_b : Wx_f;
            const float* bP  = dirp ? b_b  : b_f;
            // Wx fragments for this wave's 2 gates (B-operand: l15 = col, quad*8 = k)
            #pragma unroll
            for (int f = 0; f < 32; ++f) {
                const int ks = f >> 1, nt2 = f & 1;
                const int zc = (nh * 2 + nt2) * H_ + j0p + l15;
                const int kb = ks * 32 + quad * 8;
                v8us tmp;
                #pragma unroll
                for (int e = 0; e < 8; ++e)
                    tmp[e] = f2bf(WxP[(size_t)(kb + e) * G_ + zc]);
                bfr[f] = __builtin_bit_cast(v8bf, tmp);
            }
            const float bv0 = bP[(nh * 2 + 0) * H_ + j0p + l15];
            const float bv1 = bP[(nh * 2 + 1) * H_ + j0p + l15];
            const int t0 = th * 256;

            stageX(t0, Ab0);
            __syncthreads();
            for (int i = 0; i < 256; ++i) {
                const int t = t0 + i;
                u16* cur = (i & 1) ? Ab1 : Ab0;
                if (i + 1 < 256) stageX(t0 + i + 1, (i & 1) ? Ab0 : Ab1);
                v4f a0 = {bv0, bv0, bv0, bv0};
                v4f a1 = {bv1, bv1, bv1, bv1};
                #pragma unroll
                for (int ks = 0; ks < 16; ++ks) {
                    v8bf a = *(const v8bf*)(cur + arp + ks * 32);
                    a0 = MFMA(a, bfr[ks * 2],     a0);
                    a1 = MFMA(a, bfr[ks * 2 + 1], a1);
                }
                // direct f16 stores (plain cached; flushed by wbl2 below)
                u16* xzb = xz + ((size_t)(dirp * 64 + widp) * 512 + t) * 4096;
                #pragma unroll
                for (int r = 0; r < 4; ++r) {
                    const int row = mq * 16 + quad * 4 + r;
                    xzb[row * 64 + (nh * 2 + 0) * 16 + l15] = f2h(a0[r]);
                    xzb[row * 64 + (nh * 2 + 1) * 16 + l15] = f2h(a1[r]);
                }
                __syncthreads();   // drains next-stage + stores; protects buffer reuse
            }
        }
        // flush xz to coherence point, signal done
        asm volatile("s_waitcnt vmcnt(0)" ::: "memory");
        __syncthreads();
        if (tid == 0) {
            __builtin_amdgcn_fence(__ATOMIC_RELEASE, "agent");   // wbl2 (one-time)
            __hip_atomic_store(gen + 128 + wg, 1, __ATOMIC_RELAXED,
                               __HIP_MEMORY_SCOPE_AGENT);
        }
    }

    // ================= scan setup =================
    const int dir = wg & 1;
    const int wid = wg >> 1;
    const int j0  = wid * NJ;
    const float* Wh = dir ? Wh_b : Wh_f;

    const int kh = w & 1;                  // K-half of h (cols kh*512..)
    const int np = (w >> 1) & 1;           // gate pair
    const int mh = w >> 2;                 // 32-row half

    // Wh fragments (overlaps other WGs finishing phase 0)
    #pragma unroll
    for (int f = 0; f < 32; ++f) {
        const int ks = f >> 1, nt2 = f & 1;
        const int zc = (np * 2 + nt2) * H_ + j0 + l15;
        const int kb = kh * 512 + ks * 32 + quad * 8;
        v8us tmp;
        #pragma unroll
        for (int e = 0; e < 8; ++e)
            tmp[e] = f2bf(Wh[(size_t)(kb + e) * G_ + zc]);
        bfr[f] = __builtin_bit_cast(v8bf, tmp);
    }

    // grid-wide sync: wait all 128 done flags
    if (w == 0) {
        const int* gpa = gen + 128 + lane;
        while (!__all(__hip_atomic_load(gpa, __ATOMIC_RELAXED,
                                        __HIP_MEMORY_SCOPE_AGENT) != 0)) { }
        const int* gpb = gen + 192 + lane;
        while (!__all(__hip_atomic_load(gpb, __ATOMIC_RELAXED,
                                        __HIP_MEMORY_SCOPE_AGENT) != 0)) { }
    }
    __syncthreads();

    // epilogue ownership: 512 threads <-> 64 b x 8 col-pairs
    const int ejj = (tid & 7) * 2, eb = tid >> 3;
    float c0s = 0.0f, c1s = 0.0f;

    const int ar0 = (mh * 32 + l15) * APE + quad * 8;
    const int ar1 = ar0 + 16 * APE;

    // ================= scan loop =================
    for (int s = 0; s < T_; ++s) {
        const int t  = dir ? (T_ - 1 - s) : s;
        const int pr = s & 1, pw = pr ^ 1;
        const u16* hbR = hb + (size_t)(pr * 2 + dir) * B_ * H_;

        // 0. prefetch xz (plain cached; bias already folded in)
        const u16* xzt = xz + ((size_t)(dir * 64 + wid) * 512 + t) * 4096 + eb * 64 + ejj;
        const unsigned xw0 = *(const unsigned*)(xzt);
        const unsigned xw1 = *(const unsigned*)(xzt + 16);
        const unsigned xw2 = *(const unsigned*)(xzt + 32);
        const unsigned xw3 = *(const unsigned*)(xzt + 48);

        // 1. wave0 polls generation flags
        if (w == 0) {
            const int* gp = gen + dir * 64 + lane;
            while (!__all(__hip_atomic_load(gp, __ATOMIC_RELAXED,
                                            __HIP_MEMORY_SCOPE_AGENT) >= s)) { }
        }
        __syncthreads();                                   // b1
        // 2. stage h: cols 0..511 -> Ab0, cols 512..1023 -> Ab1 (coherent)
        #pragma unroll
        for (int r = 0; r < 8; ++r)
            gl_lds_c(hbR + (srow + r) * H_ + loff, Ab0 + (srow + r) * APE);
        #pragma unroll
        for (int r = 0; r < 8; ++r)
            gl_lds_c(hbR + (srow + r) * H_ + 512 + loff, Ab1 + (srow + r) * APE);
        __syncthreads();                                   // b2 (drains stages)
        // 3. compute: this wave's K-half, 2 m-tiles x 2 gates
        const u16* Abk = kh ? Ab1 : Ab0;
        v4f acc00 = {0.f,0.f,0.f,0.f}, acc01 = {0.f,0.f,0.f,0.f};
        v4f acc10 = {0.f,0.f,0.f,0.f}, acc11 = {0.f,0.f,0.f,0.f};
        #pragma unroll
        for (int ks = 0; ks < 16; ++ks) {
            v8bf a0 = *(const v8bf*)(Abk + ar0 + ks * 32);
            v8bf a1 = *(const v8bf*)(Abk + ar1 + ks * 32);
            acc00 = MFMA(a0, bfr[ks * 2],     acc00);
            acc01 = MFMA(a0, bfr[ks * 2 + 1], acc01);
            acc10 = MFMA(a1, bfr[ks * 2],     acc10);
            acc11 = MFMA(a1, bfr[ks * 2 + 1], acc11);
        }
        __syncthreads();                                   // b3 (all A-reads done before Cl overlay)
        // 4. write C partials (C layout: col = lane&15, row = quad*4+reg)
        {
            float* Cw = Cl + kh * (64 * CLP);
            const int c0 = (np * 2 + 0) * 16 + l15;
            const int c1 = (np * 2 + 1) * 16 + l15;
            #pragma unroll
            for (int r = 0; r < 4; ++r) {
                const int rA = (mh * 32 + quad * 4 + r) * CLP;
                const int rB = (mh * 32 + 16 + quad * 4 + r) * CLP;
                Cw[rA + c0] = acc00[r];
                Cw[rA + c1] = acc01[r];
                Cw[rB + c0] = acc10[r];
                Cw[rB + c1] = acc11[r];
            }
        }
        __syncthreads();                                   // b4
        // 5. epilogue: z = C0 + C1 + xz ; gates ; c,h
        {
            const float* C0 = Cl + eb * CLP;
            const float* C1 = Cl + (64 + eb) * CLP;
            float2 pi0 = *(const float2*)(C0 + ejj);
            float2 pf0 = *(const float2*)(C0 + 16 + ejj);
            float2 po0 = *(const float2*)(C0 + 32 + ejj);
            float2 pg0 = *(const float2*)(C0 + 48 + ejj);
            float2 pi1 = *(const float2*)(C1 + ejj);
            float2 pf1 = *(const float2*)(C1 + 16 + ejj);
            float2 po1 = *(const float2*)(C1 + 32 + ejj);
            float2 pg1 = *(const float2*)(C1 + 48 + ejj);
            float iv0 = sigm(pi0.x + pi1.x + f16lo(xw0));
            float iv1 = sigm(pi0.y + pi1.y + f16hi(xw0));
            float fv0 = sigm(pf0.x + pf1.x + f16lo(xw1));
            float fv1 = sigm(pf0.y + pf1.y + f16hi(xw1));
            float ov0 = sigm(po0.x + po1.x + f16lo(xw2));
            float ov1 = sigm(po0.y + po1.y + f16hi(xw2));
            float gv0 = tanh_f(pg0.x + pg1.x + f16lo(xw3));
            float gv1 = tanh_f(pg0.y + pg1.y + f16hi(xw3));
            float cv0 = fv0 * c0s + iv0 * gv0; c0s = cv0;
            float cv1 = fv1 * c1s + iv1 * gv1; c1s = cv1;
            float hv0 = ov0 * tanh_f(cv0);
            float hv1 = ov1 * tanh_f(cv1);
            // h: packed 2x bf16, device-coherent write-through
            unsigned hp = (unsigned)f2bf(hv0) | ((unsigned)f2bf(hv1) << 16);
            __hip_atomic_store(
                (unsigned*)(hb + (size_t)(pw * 2 + dir) * B_ * H_ + (size_t)eb * H_ + j0 + ejj),
                hp, __ATOMIC_RELAXED, __HIP_MEMORY_SCOPE_AGENT);
            float2 o2; o2.x = hv0; o2.y = hv1;
            *(float2*)(out + ((size_t)eb * T_ + t) * (2 * H_) + dir * H_ + j0 + ejj) = o2;
        }
        // 6. publish
        __syncthreads();                                   // b5 (drains all h stores)
        if (tid == 0) {
            asm volatile("s_waitcnt vmcnt(0)" ::: "memory");
            __hip_atomic_store(gen + dir * 64 + wid, s + 1, __ATOMIC_RELAXED,
                               __HIP_MEMORY_SCOPE_AGENT);
        }
    }
}

extern "C" void kernel_launch(void* const* d_in, const int* in_sizes, int n_in,
                              void* d_out, int out_size, void* d_ws, size_t ws_size,
                              hipStream_t stream) {
    const float* xin  = (const float*)d_in[0];
    const float* Wx_f = (const float*)d_in[1];
    const float* Wh_f = (const float*)d_in[2];
    const float* b_f  = (const float*)d_in[3];
    const float* Wx_b = (const float*)d_in[4];
    const float* Wh_b = (const float*)d_in[5];
    const float* b_b  = (const float*)d_in[6];
    float* out = (float*)d_out;

    // workspace layout: hb (512KB) | gen (4KB) | xT (32MB) | xz (512MB f16)
    u16* hb  = (u16*)d_ws;
    int* gen = (int*)((char*)d_ws + 524288);
    u16* xT  = (u16*)((char*)d_ws + 528384);
    u16* xz  = (u16*)((char*)d_ws + 528384 + (size_t)T_ * B_ * D_ * 2);

    hipLaunchKernelGGL(prep_kernel, dim3((B_ * T_ * (D_ / 4)) / 256), dim3(256), 0,
                       stream, xin, xT, hb, gen);

    hipFuncSetAttribute(reinterpret_cast<const void*>(scan_kernel),
                        hipFuncAttributeMaxDynamicSharedMemorySize, LDS_TOTAL);

    void* args[] = {(void*)&Wx_f, (void*)&Wh_f, (void*)&b_f,
                    (void*)&Wx_b, (void*)&Wh_b, (void*)&b_b,
                    (void*)&xT, (void*)&hb, (void*)&gen, (void*)&xz, (void*)&out};
    hipLaunchCooperativeKernel(reinterpret_cast<void*>(scan_kernel),
                               dim3(WGS), dim3(512), args, LDS_TOTAL, stream);
}

// Round 3
// 4345.978 us; speedup vs baseline: 1.0359x; 1.0359x over previous
//
#include <hip/hip_runtime.h>
#include <hip/hip_bf16.h>

#define B_ 64
#define T_ 512
#define D_ 512
#define H_ 1024
#define G_ 4096
#define NJ 16              // j-columns per wg
#define WGS 128            // 1 wg/CU on half the chip (latency-bound)
#define APE 520            // A-chunk row stride in u16 (1040 B = 1024 + 16 pad) -> uniform-8 b128 slots
#define ABUF_B (64 * APE * 2)          // 66560 B per A chunk buffer
#define CLP 268            // Cl row stride in floats ([64][67][4] layout, 1072 B/row)
#define LDS_TOTAL (2 * ABUF_B)         // 133120 B; Cl (68608 B) overlays Ab0 + first 2KB of Ab1

typedef unsigned short u16;
typedef __bf16 v8bf __attribute__((ext_vector_type(8)));
typedef unsigned short v8us __attribute__((ext_vector_type(8)));
typedef float v4f __attribute__((ext_vector_type(4)));

#define MFMA(a, b, c) __builtin_amdgcn_mfma_f32_16x16x32_bf16(a, b, c, 0, 0, 0)

__device__ __forceinline__ u16 f2bf(float f) {
    unsigned u = __builtin_bit_cast(unsigned, f);
    u += 0x7fffu + ((u >> 16) & 1u);   // RNE
    return (u16)(u >> 16);
}
__device__ __forceinline__ float sigm(float x) { return 1.0f / (1.0f + __expf(-x)); }
__device__ __forceinline__ float tanh_f(float x) { return 1.0f - 2.0f / (__expf(2.0f * x) + 1.0f); }

// async global->LDS, 16B/lane; lds dst wave-uniform base (lane*16 implicit)
__device__ __forceinline__ void gl_lds(const u16* g, u16* l) {
    __builtin_amdgcn_global_load_lds(
        (const __attribute__((address_space(1))) unsigned int*)g,
        (__attribute__((address_space(3))) unsigned int*)l, 16, 0, 0);
}
// device-coherent variant: cpol 17 = sc0 sc1 (read at LLC coherence point)
__device__ __forceinline__ void gl_lds_c(const u16* g, u16* l) {
    __builtin_amdgcn_global_load_lds(
        (const __attribute__((address_space(1))) unsigned int*)g,
        (__attribute__((address_space(3))) unsigned int*)l, 16, 0, 17);
}

// barrier helpers: counted-drain (none) and full-vm-drain barriers, fenced vs compiler motion
__device__ __forceinline__ void bar_only() {
    __builtin_amdgcn_sched_barrier(0);
    __builtin_amdgcn_s_barrier();
    __builtin_amdgcn_sched_barrier(0);
}
__device__ __forceinline__ void bar_vm0() {
    asm volatile("s_waitcnt vmcnt(0)" ::: "memory");
    __builtin_amdgcn_s_barrier();
    __builtin_amdgcn_sched_barrier(0);
}

// ---------------- pre-pass: x -> [T,B,D] bf16, zero h0 + flags ----------------
__global__ void prep_kernel(const float* __restrict__ xin, u16* __restrict__ xT,
                            u16* __restrict__ hb, int* __restrict__ gen) {
    int gid = blockIdx.x * 256 + threadIdx.x;           // over B*T*(D/4) = 4.19M
    if (gid < 65536) ((unsigned int*)hb)[gid] = 0u;     // parity-0 h buffers (256 KB)
    if (gid < 256) gen[gid] = 0;                        // generation flags (2 dirs x 64)
    int d0 = (gid & 127) * 4;
    int bt = gid >> 7;
    int b = bt >> 9, t = bt & 511;
    float4 v = *(const float4*)(xin + (size_t)bt * D_ + d0);
    ushort4 o;
    o.x = f2bf(v.x); o.y = f2bf(v.y); o.z = f2bf(v.z); o.w = f2bf(v.w);
    *(ushort4*)(xT + ((size_t)t * B_ + b) * D_ + d0) = o;
}

// ---------------- persistent scan kernel ----------------
// 128 wgs x 512 threads (8 waves), 1 wg/CU, 2 waves/SIMD.
// Wave tiling (2m x 1n x 4k): mh = w>>2 (32-row half), kq = w&3 (K-quarter of 1536).
// Each wave: M=32 rows, ALL 64 out-cols (4 gates x 16), K=384 (4 ks per 512-chunk).
// -> LDS A-read amplification 1x (192 KB/step/CU vs round-1's 768 KB).
// W frags in regs: 3 chunks x 4 ks x 4 gates = 48 x v8bf (192 regs, proven-resident budget).
// K-partials: Cl[64 rows][67 colslots][4 parts] f32 overlays Ab0 (+2KB of Ab1);
//   safe: written after b3.5 (post phase2), consumed before b5, restaged at s+1 post-poll.
// Coherence: h via sc0 sc1 write-through / LLC reads; flags dense per-WG (no RMW, no fences).
extern "C" __global__ void __launch_bounds__(512, 2)
scan_kernel(const float* __restrict__ Wx_f, const float* __restrict__ Wh_f,
            const float* __restrict__ b_f,
            const float* __restrict__ Wx_b, const float* __restrict__ Wh_b,
            const float* __restrict__ b_b,
            const u16* __restrict__ xT, u16* __restrict__ hb,
            int* __restrict__ gen, float* __restrict__ out) {
    extern __shared__ char smem[];
    u16* Ab0 = (u16*)smem;
    u16* Ab1 = (u16*)(smem + ABUF_B);
    float* Cl = (float*)smem;              // [64][67][4] f32, overlays Ab0

    const int tid = threadIdx.x;
    const int wg  = blockIdx.x;
    const int dir = wg & 1;
    const int wid = wg >> 1;               // 0..63
    const int j0  = wid * NJ;

    const float* Wx   = dir ? Wx_b : Wx_f;
    const float* Wh   = dir ? Wh_b : Wh_f;
    const float* bias = dir ? b_b  : b_f;

    const int w    = tid >> 6;
    const int lane = tid & 63;
    const int quad = lane >> 4;
    const int l15  = lane & 15;
    const int kq = w & 3;                  // K-quarter
    const int mh = w >> 2;                 // 32-row half

    // ---- one-time: W fragments (B-operand: l15 = col, quad*8+e = k) ----
    // frag f = (c*4 + j)*4 + g : chunk c (0..2), local ks j (0..3), gate g (0..3)
    v8bf bfr[48];
    #pragma unroll
    for (int c = 0; c < 3; ++c) {
        #pragma unroll
        for (int j = 0; j < 4; ++j) {
            const int kb = c * 512 + (kq * 4 + j) * 32 + quad * 8;
            #pragma unroll
            for (int g = 0; g < 4; ++g) {
                const int zc = g * H_ + j0 + l15;
                v8us tmp;
                #pragma unroll
                for (int e = 0; e < 8; ++e) {
                    int k = kb + e;
                    float wv = (k < D_) ? Wx[(size_t)k * G_ + zc]
                                        : Wh[(size_t)(k - D_) * G_ + zc];
                    tmp[e] = f2bf(wv);
                }
                bfr[(c * 4 + j) * 4 + g] = __builtin_bit_cast(v8bf, tmp);
            }
        }
    }

    // epilogue ownership: 512 threads <-> 64 b x 8 col-pairs
    const int ejj = (tid & 7) * 2, eb = tid >> 3;
    const float2 bI = *(const float2*)(bias + j0 + ejj);
    const float2 bF = *(const float2*)(bias + H_ + j0 + ejj);
    const float2 bO = *(const float2*)(bias + 2 * H_ + j0 + ejj);
    const float2 bG = *(const float2*)(bias + 3 * H_ + j0 + ejj);
    float c0s = 0.0f, c1s = 0.0f;

    // A-frag LDS offsets (u16); row stride APE=520 -> slot index (row+quad+4(ks&1))%8 uniform-8
    const int ar0 = (mh * 32 + l15) * APE + quad * 8;
    const int ar1 = ar0 + 16 * APE;
    const int srow = w * 8;                 // staging rows w*8..w*8+7
    const int loff = lane * 8;              // 16B per lane

    v4f acc0[4], acc1[4];

    for (int s = 0; s < T_; ++s) {
        const int t  = dir ? (T_ - 1 - s) : s;
        const int pr = s & 1, pw = pr ^ 1;
        const u16* hbR = hb + (size_t)(pr * 2 + dir) * B_ * H_;

        // 1. stage c0 = x_t (K 0..511) into Ab0 — cached, no dependency on h
        {
            const u16* src = xT + (size_t)t * B_ * D_;
            #pragma unroll
            for (int r = 0; r < 8; ++r)
                gl_lds(src + (srow + r) * D_ + loff, Ab0 + (srow + r) * APE);
        }
        // 2. ALL waves poll (each drains its own vmcnt incl. c0 when reading flags)
        {
            const int* gp = gen + dir * 64 + lane;
            while (!__all(__hip_atomic_load(gp, __ATOMIC_RELAXED,
                                            __HIP_MEMORY_SCOPE_AGENT) >= s)) { }
        }
        // 3. stage c1 = h cols 0..511 (K 512..1023) into Ab1 — coherent, flight under phase0
        #pragma unroll
        for (int r = 0; r < 8; ++r)
            gl_lds_c(hbR + (srow + r) * H_ + loff, Ab1 + (srow + r) * APE);
        bar_only();                         // b1: Ab0 complete (everyone staged+drained via poll)
        // 4. phase0: x-part (chunk 0) from Ab0
        #pragma unroll
        for (int g = 0; g < 4; ++g) { acc0[g] = (v4f){0.f,0.f,0.f,0.f}; acc1[g] = (v4f){0.f,0.f,0.f,0.f}; }
        #pragma unroll
        for (int j = 0; j < 4; ++j) {
            const int ko = (kq * 4 + j) * 32;
            v8bf a0 = *(const v8bf*)(Ab0 + ar0 + ko);
            v8bf a1 = *(const v8bf*)(Ab0 + ar1 + ko);
            #pragma unroll
            for (int g = 0; g < 4; ++g) {
                acc0[g] = MFMA(a0, bfr[j * 4 + g], acc0[g]);
                acc1[g] = MFMA(a1, bfr[j * 4 + g], acc1[g]);
            }
        }
        bar_vm0();                          // b2: c1 landed everywhere; Ab0 reads done
        // 5. stage c2 = h cols 512..1023 (K 1024..1535) into Ab0 — coherent, flight under phase1
        #pragma unroll
        for (int r = 0; r < 8; ++r)
            gl_lds_c(hbR + (srow + r) * H_ + 512 + loff, Ab0 + (srow + r) * APE);
        // 6. phase1: h-lo (chunk 1) from Ab1
        #pragma unroll
        for (int j = 0; j < 4; ++j) {
            const int ko = (kq * 4 + j) * 32;
            v8bf a0 = *(const v8bf*)(Ab1 + ar0 + ko);
            v8bf a1 = *(const v8bf*)(Ab1 + ar1 + ko);
            #pragma unroll
            for (int g = 0; g < 4; ++g) {
                acc0[g] = MFMA(a0, bfr[16 + j * 4 + g], acc0[g]);
                acc1[g] = MFMA(a1, bfr[16 + j * 4 + g], acc1[g]);
            }
        }
        bar_vm0();                          // b3: c2 landed; Ab1 reads done
        // 7. phase2: h-hi (chunk 2) from Ab0
        #pragma unroll
        for (int j = 0; j < 4; ++j) {
            const int ko = (kq * 4 + j) * 32;
            v8bf a0 = *(const v8bf*)(Ab0 + ar0 + ko);
            v8bf a1 = *(const v8bf*)(Ab0 + ar1 + ko);
            #pragma unroll
            for (int g = 0; g < 4; ++g) {
                acc0[g] = MFMA(a0, bfr[32 + j * 4 + g], acc0[g]);
                acc1[g] = MFMA(a1, bfr[32 + j * 4 + g], acc1[g]);
            }
        }
        __syncthreads();                    // b3.5: all Ab0 reads done before Cl overlay
        // 8. write k-partials: Cl[row][col][kq]  (C layout: col = l15, row = quad*4+reg)
        #pragma unroll
        for (int g = 0; g < 4; ++g) {
            const int cs = (g * 16 + l15) * 4 + kq;
            #pragma unroll
            for (int r = 0; r < 4; ++r) {
                Cl[(mh * 32 + quad * 4 + r) * CLP + cs]      = acc0[g][r];
                Cl[(mh * 32 + 16 + quad * 4 + r) * CLP + cs] = acc1[g][r];
            }
        }
        __syncthreads();                    // b4
        // 9. epilogue: z = sum of 4 partials + bias ; gates ; c,h
        float hv0, hv1;
        {
            const float* C0 = Cl + eb * CLP;
            v4f pi0 = *(const v4f*)(C0 + (0 * 16 + ejj) * 4);
            v4f pi1 = *(const v4f*)(C0 + (0 * 16 + ejj + 1) * 4);
            v4f pf0 = *(const v4f*)(C0 + (1 * 16 + ejj) * 4);
            v4f pf1 = *(const v4f*)(C0 + (1 * 16 + ejj + 1) * 4);
            v4f po0 = *(const v4f*)(C0 + (2 * 16 + ejj) * 4);
            v4f po1 = *(const v4f*)(C0 + (2 * 16 + ejj + 1) * 4);
            v4f pg0 = *(const v4f*)(C0 + (3 * 16 + ejj) * 4);
            v4f pg1 = *(const v4f*)(C0 + (3 * 16 + ejj + 1) * 4);
            float zi0 = (pi0[0] + pi0[1]) + (pi0[2] + pi0[3]) + bI.x;
            float zi1 = (pi1[0] + pi1[1]) + (pi1[2] + pi1[3]) + bI.y;
            float zf0 = (pf0[0] + pf0[1]) + (pf0[2] + pf0[3]) + bF.x;
            float zf1 = (pf1[0] + pf1[1]) + (pf1[2] + pf1[3]) + bF.y;
            float zo0 = (po0[0] + po0[1]) + (po0[2] + po0[3]) + bO.x;
            float zo1 = (po1[0] + po1[1]) + (po1[2] + po1[3]) + bO.y;
            float zg0 = (pg0[0] + pg0[1]) + (pg0[2] + pg0[3]) + bG.x;
            float zg1 = (pg1[0] + pg1[1]) + (pg1[2] + pg1[3]) + bG.y;
            float iv0 = sigm(zi0), iv1 = sigm(zi1);
            float fv0 = sigm(zf0), fv1 = sigm(zf1);
            float ov0 = sigm(zo0), ov1 = sigm(zo1);
            float gv0 = tanh_f(zg0), gv1 = tanh_f(zg1);
            float cv0 = fv0 * c0s + iv0 * gv0; c0s = cv0;
            float cv1 = fv1 * c1s + iv1 * gv1; c1s = cv1;
            hv0 = ov0 * tanh_f(cv0);
            hv1 = ov1 * tanh_f(cv1);
            // h: packed 2x bf16, device-coherent write-through (at LLC when vmcnt drains)
            unsigned hp = (unsigned)f2bf(hv0) | ((unsigned)f2bf(hv1) << 16);
            __hip_atomic_store(
                (unsigned*)(hb + (size_t)(pw * 2 + dir) * B_ * H_ + (size_t)eb * H_ + j0 + ejj),
                hp, __ATOMIC_RELAXED, __HIP_MEMORY_SCOPE_AGENT);
        }
        // 10. publish: b5 drains every wave's h stores, then one plain coherent flag store
        __syncthreads();                    // b5
        if (tid == 0) {
            asm volatile("s_waitcnt vmcnt(0)" ::: "memory");
            __hip_atomic_store(gen + dir * 64 + wid, s + 1, __ATOMIC_RELAXED,
                               __HIP_MEMORY_SCOPE_AGENT);
        }
        // 11. out store AFTER publish — its ack drains during next step's poll
        {
            float2 o2; o2.x = hv0; o2.y = hv1;
            *(float2*)(out + ((size_t)eb * T_ + t) * (2 * H_) + dir * H_ + j0 + ejj) = o2;
        }
    }
}

extern "C" void kernel_launch(void* const* d_in, const int* in_sizes, int n_in,
                              void* d_out, int out_size, void* d_ws, size_t ws_size,
                              hipStream_t stream) {
    const float* xin  = (const float*)d_in[0];
    const float* Wx_f = (const float*)d_in[1];
    const float* Wh_f = (const float*)d_in[2];
    const float* b_f  = (const float*)d_in[3];
    const float* Wx_b = (const float*)d_in[4];
    const float* Wh_b = (const float*)d_in[5];
    const float* b_b  = (const float*)d_in[6];
    float* out = (float*)d_out;

    // workspace layout: hb (512KB) | gen (4KB) | xT (32MB)
    u16* hb  = (u16*)d_ws;
    int* gen = (int*)((char*)d_ws + 524288);
    u16* xT  = (u16*)((char*)d_ws + 528384);

    hipLaunchKernelGGL(prep_kernel, dim3((B_ * T_ * (D_ / 4)) / 256), dim3(256), 0,
                       stream, xin, xT, hb, gen);

    hipFuncSetAttribute(reinterpret_cast<const void*>(scan_kernel),
                        hipFuncAttributeMaxDynamicSharedMemorySize, LDS_TOTAL);

    void* args[] = {(void*)&Wx_f, (void*)&Wh_f, (void*)&b_f,
                    (void*)&Wx_b, (void*)&Wh_b, (void*)&b_b,
                    (void*)&xT, (void*)&hb, (void*)&gen, (void*)&out};
    hipLaunchCooperativeKernel(reinterpret_cast<void*>(scan_kernel),
                               dim3(WGS), dim3(512), args, LDS_TOTAL, stream);
}

// Round 4
// 3910.131 us; speedup vs baseline: 1.1513x; 1.1115x over previous
//
#include <hip/hip_runtime.h>
#include <hip/hip_bf16.h>

#define B_ 64
#define T_ 512
#define D_ 512
#define H_ 1024
#define G_ 4096
#define NJ 16              // j-columns per wg
#define WPD 64             // wgs per direction
#define WGS 128            // 1 wg/CU on half the chip (latency-bound)
#define APE 520            // A-chunk row stride in u16 (1040 B = 1024 + 16 pad)
#define ABUF_B (64 * APE * 2)          // 66560 B per A chunk buffer
#define CT_OFF (2 * ABUF_B)            // 133120
#define CLP 66                         // C tile row stride (floats)
#define LDS_TOTAL (CT_OFF + 64 * CLP * 4)   // 150016 B
#define HSN 67584                      // per-step h slot stride in u16 (132 KB = 128 KB data + 4 KB pad)
#define HB_BYTES 138682368             // 1026 slots x 135168 B

typedef unsigned short u16;
typedef __bf16 v8bf __attribute__((ext_vector_type(8)));
typedef unsigned short v8us __attribute__((ext_vector_type(8)));
typedef float v4f __attribute__((ext_vector_type(4)));

#define MFMA(a, b, c) __builtin_amdgcn_mfma_f32_16x16x32_bf16(a, b, c, 0, 0, 0)

__device__ __forceinline__ u16 f2bf(float f) {
    unsigned u = __builtin_bit_cast(unsigned, f);
    u += 0x7fffu + ((u >> 16) & 1u);   // RNE
    return (u16)(u >> 16);
}
__device__ __forceinline__ float sigm(float x) { return 1.0f / (1.0f + __expf(-x)); }
__device__ __forceinline__ float tanh_f(float x) { return 1.0f - 2.0f / (__expf(2.0f * x) + 1.0f); }

// async global->LDS, 16B/lane, PLAIN cached (L1+L2); lds dst wave-uniform base
__device__ __forceinline__ void gl_lds(const u16* g, u16* l) {
    __builtin_amdgcn_global_load_lds(
        (const __attribute__((address_space(1))) unsigned int*)g,
        (__attribute__((address_space(3))) unsigned int*)l, 16, 0, 0);
}

// ---------------- pre-pass: x -> [T,B,D] bf16, zero h slots 0/1 + flags ----------------
__global__ void prep_kernel(const float* __restrict__ xin, u16* __restrict__ xT,
                            u16* __restrict__ hb, int* __restrict__ gen) {
    int gid = blockIdx.x * 256 + threadIdx.x;           // over B*T*(D/4) = 4.19M
    if (gid < 67584) ((unsigned int*)hb)[gid] = 0u;     // h slots 0,1 (264 KB incl pads)
    if (gid < 256) gen[gid] = 0;                        // generation flags (2 dirs x 64)
    int d0 = (gid & 127) * 4;
    int bt = gid >> 7;
    int b = bt >> 9, t = bt & 511;
    float4 v = *(const float4*)(xin + (size_t)bt * D_ + d0);
    ushort4 o;
    o.x = f2bf(v.x); o.y = f2bf(v.y); o.z = f2bf(v.z); o.w = f2bf(v.w);
    *(ushort4*)(xT + ((size_t)t * B_ + b) * D_ + d0) = o;
}

// ---------------- persistent scan kernel ----------------
// 128 wgs x 512 threads (8 waves), 1 wg/CU, 2 waves/SIMD.
// Wave tiling (round-1, measured best): nt=w&3 (gate / 16-col n-tile), mh=w>>2 (32-row
// half). Full K=1536 per wave; W frags in VGPRs (48 x v8bf = 192 regs).
// h exchange: per-step WRITE-ONCE buffers (slot s+1 <- h of step s, slot 0 = zeros).
//   producers: sc0 sc1 write-through (LLC-visible when vmcnt drains, before flag);
//   consumers: PLAIN cached gl_lds -- first-touch per dispatch, so never stale, and
//   the ~16 WGs per XCD share one L2 copy (LLC broadcast traffic /8 vs sc0sc1 reads).
// Flags: dense per-WG generation counters, coherent polls by wave 0 only.
extern "C" __global__ void __launch_bounds__(512, 2)
scan_kernel(const float* __restrict__ Wx_f, const float* __restrict__ Wh_f,
            const float* __restrict__ b_f,
            const float* __restrict__ Wx_b, const float* __restrict__ Wh_b,
            const float* __restrict__ b_b,
            const u16* __restrict__ xT, u16* __restrict__ hb,
            int* __restrict__ gen, float* __restrict__ out) {
    extern __shared__ char smem[];
    u16* Ab0 = (u16*)smem;
    u16* Ab1 = (u16*)(smem + ABUF_B);
    float* Cl = (float*)(smem + CT_OFF);   // [64][66] f32 z values

    const int tid = threadIdx.x;
    const int wg  = blockIdx.x;
    const int dir = wg & 1;
    const int wid = wg >> 1;               // 0..63
    const int j0  = wid * NJ;

    const float* Wx   = dir ? Wx_b : Wx_f;
    const float* Wh   = dir ? Wh_b : Wh_f;
    const float* bias = dir ? b_b  : b_f;

    const int w    = tid >> 6;
    const int lane = tid & 63;
    const int quad = lane >> 4;
    const int l15  = lane & 15;
    const int nt = w & 3;                  // gate index (i,f,o,g) == n-tile
    const int mh = w >> 2;                 // 32-row half

    // ---- one-time: load W fragments into registers (B-operand: lane l15 = col) ----
    const int zc = nt * H_ + j0 + l15;
    v8bf bfr[48];
    #pragma unroll
    for (int f = 0; f < 48; ++f) {
        const int kb = f * 32 + quad * 8;
        v8us tmp;
        #pragma unroll
        for (int e = 0; e < 8; ++e) {
            int k = kb + e;
            float wv = (k < D_) ? Wx[(size_t)k * G_ + zc]
                                : Wh[(size_t)(k - D_) * G_ + zc];
            tmp[e] = f2bf(wv);
        }
        bfr[f] = __builtin_bit_cast(v8bf, tmp);
    }

    // epilogue ownership: 512 threads <-> 64 b x 8 col-pairs (16 cols)
    const int ejj = (tid & 7) * 2, eb = tid >> 3;
    const float2 bI = *(const float2*)(bias + j0 + ejj);
    const float2 bF = *(const float2*)(bias + H_ + j0 + ejj);
    const float2 bO = *(const float2*)(bias + 2 * H_ + j0 + ejj);
    const float2 bG = *(const float2*)(bias + 3 * H_ + j0 + ejj);
    float c0s = 0.0f, c1s = 0.0f;

    // A-frag LDS offsets (u16 units); row stride APE=520 -> conflict-free b128
    const int ar0 = (mh * 32 + l15) * APE + quad * 8;
    const int ar1 = ar0 + 16 * APE;
    const int srow = w * 8;                 // staging rows w*8..w*8+7
    const int loff = lane * 8;              // 16B per lane

    for (int s = 0; s < T_; ++s) {
        const int t  = dir ? (T_ - 1 - s) : s;
        const u16* hbR = hb + (size_t)(2 * s + dir) * HSN;           // write-once slot s
        u16*       hbW = hb + (size_t)(2 * (s + 1) + dir) * HSN;     // slot s+1

        // 1. stage c0 = x_t (K 0..511) into Ab0 — cached, no dependency on h
        {
            const u16* src = xT + (size_t)t * B_ * D_;
            #pragma unroll
            for (int r = 0; r < 8; ++r)
                gl_lds(src + (srow + r) * D_ + loff, Ab0 + (srow + r) * APE);
        }
        // 2. wave0 polls generation flags (coherent; repeated-read address)
        if (w == 0) {
            const int* gp = gen + dir * 64 + lane;
            while (!__all(__hip_atomic_load(gp, __ATOMIC_RELAXED,
                                            __HIP_MEMORY_SCOPE_AGENT) >= s)) { }
        }
        __syncthreads();                                   // b1 (drains c0)
        // 3. stage c1 = h cols 0..511 (K 512..1023) into Ab1 — PLAIN (first-touch, L2-shared)
        #pragma unroll
        for (int r = 0; r < 8; ++r)
            gl_lds(hbR + (srow + r) * H_ + loff, Ab1 + (srow + r) * APE);
        // 4. compute c0 (frags 0..15), overlaps c1 flight
        v4f acc0 = {0.f, 0.f, 0.f, 0.f}, acc1 = {0.f, 0.f, 0.f, 0.f};
        #pragma unroll
        for (int f = 0; f < 16; ++f) {
            v8bf a0 = *(const v8bf*)(Ab0 + ar0 + f * 32);
            v8bf a1 = *(const v8bf*)(Ab0 + ar1 + f * 32);
            acc0 = MFMA(a0, bfr[f], acc0);
            acc1 = MFMA(a1, bfr[f], acc1);
        }
        __syncthreads();                                   // b2 (drains c1)
        // 5. stage c2 = h cols 512..1023 (K 1024..1535) into Ab0 — PLAIN
        #pragma unroll
        for (int r = 0; r < 8; ++r)
            gl_lds(hbR + (srow + r) * H_ + 512 + loff, Ab0 + (srow + r) * APE);
        // 6. compute c1 (frags 16..31)
        #pragma unroll
        for (int f = 16; f < 32; ++f) {
            v8bf a0 = *(const v8bf*)(Ab1 + ar0 + (f - 16) * 32);
            v8bf a1 = *(const v8bf*)(Ab1 + ar1 + (f - 16) * 32);
            acc0 = MFMA(a0, bfr[f], acc0);
            acc1 = MFMA(a1, bfr[f], acc1);
        }
        __syncthreads();                                   // b3 (drains c2)
        // 7. compute c2 (frags 32..47)
        #pragma unroll
        for (int f = 32; f < 48; ++f) {
            v8bf a0 = *(const v8bf*)(Ab0 + ar0 + (f - 32) * 32);
            v8bf a1 = *(const v8bf*)(Ab0 + ar1 + (f - 32) * 32);
            acc0 = MFMA(a0, bfr[f], acc0);
            acc1 = MFMA(a1, bfr[f], acc1);
        }
        // 8. write z tile (C layout: col = lane&15, row = quad*4+reg)
        #pragma unroll
        for (int r = 0; r < 4; ++r) {
            Cl[(mh * 32 + quad * 4 + r) * CLP + nt * 16 + l15]      = acc0[r];
            Cl[(mh * 32 + 16 + quad * 4 + r) * CLP + nt * 16 + l15] = acc1[r];
        }
        __syncthreads();                                   // b4
        // 9. epilogue: gates, c, h  (cols: i=0..15, f=16..31, o=32..47, g=48..63)
        float hv0, hv1;
        {
            const float* C0 = Cl + eb * CLP;
            float2 zi = *(const float2*)(C0 + ejj);
            float2 zf = *(const float2*)(C0 + 16 + ejj);
            float2 zo = *(const float2*)(C0 + 32 + ejj);
            float2 zg = *(const float2*)(C0 + 48 + ejj);
            float iv0 = sigm(zi.x + bI.x), iv1 = sigm(zi.y + bI.y);
            float fv0 = sigm(zf.x + bF.x), fv1 = sigm(zf.y + bF.y);
            float ov0 = sigm(zo.x + bO.x), ov1 = sigm(zo.y + bO.y);
            float gv0 = tanh_f(zg.x + bG.x), gv1 = tanh_f(zg.y + bG.y);
            float cv0 = fv0 * c0s + iv0 * gv0; c0s = cv0;
            float cv1 = fv1 * c1s + iv1 * gv1; c1s = cv1;
            hv0 = ov0 * tanh_f(cv0);
            hv1 = ov1 * tanh_f(cv1);
            // h: packed 2x bf16, device-coherent write-through (at LLC when vmcnt drains)
            unsigned hp = (unsigned)f2bf(hv0) | ((unsigned)f2bf(hv1) << 16);
            __hip_atomic_store((unsigned*)(hbW + (size_t)eb * H_ + j0 + ejj),
                               hp, __ATOMIC_RELAXED, __HIP_MEMORY_SCOPE_AGENT);
        }
        // 10. publish: b5 drains every wave's h stores, then one plain coherent flag store
        __syncthreads();                                   // b5
        if (tid == 0) {
            asm volatile("s_waitcnt vmcnt(0)" ::: "memory");
            __hip_atomic_store(gen + dir * 64 + wid, s + 1, __ATOMIC_RELAXED,
                               __HIP_MEMORY_SCOPE_AGENT);
        }
        // 11. out store AFTER publish — off the critical chain
        {
            float2 o2; o2.x = hv0; o2.y = hv1;
            *(float2*)(out + ((size_t)eb * T_ + t) * (2 * H_) + dir * H_ + j0 + ejj) = o2;
        }
    }
}

extern "C" void kernel_launch(void* const* d_in, const int* in_sizes, int n_in,
                              void* d_out, int out_size, void* d_ws, size_t ws_size,
                              hipStream_t stream) {
    const float* xin  = (const float*)d_in[0];
    const float* Wx_f = (const float*)d_in[1];
    const float* Wh_f = (const float*)d_in[2];
    const float* b_f  = (const float*)d_in[3];
    const float* Wx_b = (const float*)d_in[4];
    const float* Wh_b = (const float*)d_in[5];
    const float* b_b  = (const float*)d_in[6];
    float* out = (float*)d_out;

    // workspace layout: hseq (132.3 MB, 1026 write-once slots) | gen (4KB) | xT (32MB)
    u16* hb  = (u16*)d_ws;
    int* gen = (int*)((char*)d_ws + HB_BYTES);
    u16* xT  = (u16*)((char*)d_ws + HB_BYTES + 4096);

    hipLaunchKernelGGL(prep_kernel, dim3((B_ * T_ * (D_ / 4)) / 256), dim3(256), 0,
                       stream, xin, xT, hb, gen);

    hipFuncSetAttribute(reinterpret_cast<const void*>(scan_kernel),
                        hipFuncAttributeMaxDynamicSharedMemorySize, LDS_TOTAL);

    void* args[] = {(void*)&Wx_f, (void*)&Wh_f, (void*)&b_f,
                    (void*)&Wx_b, (void*)&Wh_b, (void*)&b_b,
                    (void*)&xT, (void*)&hb, (void*)&gen, (void*)&out};
    hipLaunchCooperativeKernel(reinterpret_cast<void*>(scan_kernel),
                               dim3(WGS), dim3(512), args, LDS_TOTAL, stream);
}

// Round 6
// 2807.787 us; speedup vs baseline: 1.6033x; 1.3926x over previous
//
#include <hip/hip_runtime.h>
#include <hip/hip_bf16.h>

#define B_ 64
#define T_ 512
#define D_ 512
#define H_ 1024
#define G_ 4096
#define NJ 16              // j-columns per wg
#define WGS 256            // 2 dirs x 2 row-halves x 64 col-groups; 1 wg/CU, full chip
#define RPW 32             // batch rows per wg
#define APE 520            // A-chunk row stride in u16 (1040 B = 1024 + 16 pad)
#define CHUNK_B (RPW * APE * 2)        // 33280 B per A chunk buffer
#define CL_OFF (3 * CHUNK_B)           // 99840
#define CLP 66                         // C tile row stride (floats)
#define LDS_TOTAL (CL_OFF + RPW * CLP * 4)   // 108288 B
#define HBUF (RPW * H_)                // u16 per h buffer (32 rows x 1024)

typedef unsigned short u16;
typedef __bf16 v8bf __attribute__((ext_vector_type(8)));
typedef unsigned short v8us __attribute__((ext_vector_type(8)));
typedef float v4f __attribute__((ext_vector_type(4)));

#define MFMA(a, b, c) __builtin_amdgcn_mfma_f32_16x16x32_bf16(a, b, c, 0, 0, 0)

__device__ __forceinline__ u16 f2bf(float f) {
    unsigned u = __builtin_bit_cast(unsigned, f);
    u += 0x7fffu + ((u >> 16) & 1u);   // RNE
    return (u16)(u >> 16);
}
__device__ __forceinline__ float sigm(float x) { return 1.0f / (1.0f + __expf(-x)); }
__device__ __forceinline__ float tanh_f(float x) { return 1.0f - 2.0f / (__expf(2.0f * x) + 1.0f); }

// async global->LDS, 16B/lane; lds dst wave-uniform base (lane*16 implicit)
__device__ __forceinline__ void gl_lds(const u16* g, u16* l) {
    __builtin_amdgcn_global_load_lds(
        (const __attribute__((address_space(1))) unsigned int*)g,
        (__attribute__((address_space(3))) unsigned int*)l, 16, 0, 0);
}
// device-coherent variant: cpol 17 = sc0 sc1 (read at LLC coherence point) -- R1-proven
__device__ __forceinline__ void gl_lds_c(const u16* g, u16* l) {
    __builtin_amdgcn_global_load_lds(
        (const __attribute__((address_space(1))) unsigned int*)g,
        (__attribute__((address_space(3))) unsigned int*)l, 16, 0, 17);
}

__device__ __forceinline__ void bar_only() {
    __builtin_amdgcn_sched_barrier(0);
    asm volatile("s_waitcnt lgkmcnt(0)" ::: "memory");
    __builtin_amdgcn_s_barrier();
    __builtin_amdgcn_sched_barrier(0);
}
// counted-drain barrier: wait until <=4 vmem outstanding, then barrier
__device__ __forceinline__ void bar_vm4() {
    __builtin_amdgcn_sched_barrier(0);
    asm volatile("s_waitcnt vmcnt(4) lgkmcnt(0)" ::: "memory");
    __builtin_amdgcn_s_barrier();
    __builtin_amdgcn_sched_barrier(0);
}
__device__ __forceinline__ void bar_vm0() {
    __builtin_amdgcn_sched_barrier(0);
    asm volatile("s_waitcnt vmcnt(0) lgkmcnt(0)" ::: "memory");
    __builtin_amdgcn_s_barrier();
    __builtin_amdgcn_sched_barrier(0);
}

// ---------------- pre-pass: x -> [T,B,D] bf16, zero h parity-0 + flags ----------------
__global__ void prep_kernel(const float* __restrict__ xin, u16* __restrict__ xT,
                            u16* __restrict__ hb, int* __restrict__ gen) {
    int gid = blockIdx.x * 256 + threadIdx.x;           // over B*T*(D/4) = 4.19M
    if (gid < 65536) ((unsigned int*)hb)[gid] = 0u;     // parity-0 h buffers (4 x 64 KB)
    if (gid < 256) gen[gid] = 0;                        // flags: 4 domains x 64
    int d0 = (gid & 127) * 4;
    int bt = gid >> 7;
    int b = bt >> 9, t = bt & 511;
    float4 v = *(const float4*)(xin + (size_t)bt * D_ + d0);
    ushort4 o;
    o.x = f2bf(v.x); o.y = f2bf(v.y); o.z = f2bf(v.z); o.w = f2bf(v.w);
    *(ushort4*)(xT + ((size_t)t * B_ + b) * D_ + d0) = o;
}

// ---------------- persistent scan kernel ----------------
// 256 wgs x 512 threads (8 waves), 1 wg/CU.
// wg: dir=wg&1, rh=(wg>>1)&1 (32-row batch half), wid=wg>>2 (col group, j0=wid*16).
// 4 independent chains (dir x rh); flag domain = 64 WGs each.
// wave w: nt=w&3 (gate n-tile), mt=w>>2 (16-row m-tile). Full K=1536 per wave,
// 48 W frags in regs. LDS: X0|H1|H2 chunks (32 rows x 512 cols each) + Cl[32][66].
// KEY: both h chunks issued back-to-back after poll -> LLC latencies overlap
// (bar_vm4 after phase0 waits c1 only; bar_vm0 after phase1 waits c2).
// Next-step x prefetched into X0 during phase2 (drained by b4's __syncthreads).
extern "C" __global__ void __launch_bounds__(512, 2)
scan_kernel(const float* __restrict__ Wx_f, const float* __restrict__ Wh_f,
            const float* __restrict__ b_f,
            const float* __restrict__ Wx_b, const float* __restrict__ Wh_b,
            const float* __restrict__ b_b,
            const u16* __restrict__ xT, u16* __restrict__ hb,
            int* __restrict__ gen, float* __restrict__ out) {
    extern __shared__ char smem[];
    u16* X0 = (u16*)smem;
    u16* H1 = (u16*)(smem + CHUNK_B);
    u16* H2 = (u16*)(smem + 2 * CHUNK_B);
    float* Cl = (float*)(smem + CL_OFF);   // [32][66] f32 z values

    const int tid = threadIdx.x;
    const int wg  = blockIdx.x;
    const int dir = wg & 1;
    const int rh  = (wg >> 1) & 1;
    const int wid = wg >> 2;               // 0..63
    const int j0  = wid * NJ;
    const int dom = dir * 2 + rh;          // chain id

    const float* Wx   = dir ? Wx_b : Wx_f;
    const float* Wh   = dir ? Wh_b : Wh_f;
    const float* bias = dir ? b_b  : b_f;

    const int w    = tid >> 6;
    const int lane = tid & 63;
    const int quad = lane >> 4;
    const int l15  = lane & 15;
    const int nt = w & 3;                  // gate index (i,f,o,g) == n-tile
    const int mt = w >> 2;                 // 16-row m-tile

    // ---- one-time: load W fragments into registers (B-operand: lane l15 = col) ----
    const int zc = nt * H_ + j0 + l15;
    v8bf bfr[48];
    #pragma unroll
    for (int f = 0; f < 48; ++f) {
        const int kb = f * 32 + quad * 8;
        v8us tmp;
        #pragma unroll
        for (int e = 0; e < 8; ++e) {
            int k = kb + e;
            float wv = (k < D_) ? Wx[(size_t)k * G_ + zc]
                                : Wh[(size_t)(k - D_) * G_ + zc];
            tmp[e] = f2bf(wv);
        }
        bfr[f] = __builtin_bit_cast(v8bf, tmp);
    }

    // epilogue ownership: 512 threads <-> 32 rows x 16 cols, 1 elem/thread
    const int ejj = tid & 15, eb = tid >> 4;
    const float bI = bias[j0 + ejj];
    const float bF = bias[H_ + j0 + ejj];
    const float bO = bias[2 * H_ + j0 + ejj];
    const float bG = bias[3 * H_ + j0 + ejj];
    float cst = 0.0f;

    // A-frag LDS offsets (u16); row stride APE=520 -> conflict-free b128
    const int ar = (mt * 16 + l15) * APE + quad * 8;
    const int srow = w * 4;                 // staging rows w*4..w*4+3
    const int loff = lane * 8;              // 16B per lane

    // prologue: stage x for s=0
    {
        const int t0 = dir ? (T_ - 1) : 0;
        const u16* src = xT + (size_t)t0 * B_ * D_ + (size_t)(rh * RPW) * D_;
        #pragma unroll
        for (int r = 0; r < 4; ++r)
            gl_lds(src + (srow + r) * D_ + loff, X0 + (srow + r) * APE);
    }
    __syncthreads();

    for (int s = 0; s < T_; ++s) {
        const int t  = dir ? (T_ - 1 - s) : s;
        const int pr = s & 1, pw = pr ^ 1;
        const u16* hbR = hb + (size_t)(pr * 4 + dom) * HBUF;
        u16*       hbW = hb + (size_t)(pw * 4 + dom) * HBUF;

        // 1. wave0 polls this chain's 64 generation flags
        if (w == 0) {
            const int* gp = gen + dom * 64 + lane;
            while (!__all(__hip_atomic_load(gp, __ATOMIC_RELAXED,
                                            __HIP_MEMORY_SCOPE_AGENT) >= s)) { }
        }
        bar_only();                                        // b1 (X0 drained at prev b4)
        // 2. issue BOTH h chunks back-to-back (coherent) -> latencies overlap
        #pragma unroll
        for (int r = 0; r < 4; ++r)
            gl_lds_c(hbR + (srow + r) * H_ + loff, H1 + (srow + r) * APE);
        #pragma unroll
        for (int r = 0; r < 4; ++r)
            gl_lds_c(hbR + (srow + r) * H_ + 512 + loff, H2 + (srow + r) * APE);
        // 3. phase0: x-part from X0 (frags 0..15), two interleaved acc chains
        v4f accE = {0.f, 0.f, 0.f, 0.f}, accO = {0.f, 0.f, 0.f, 0.f};
        #pragma unroll
        for (int f = 0; f < 16; f += 2) {
            v8bf a0 = *(const v8bf*)(X0 + ar + f * 32);
            v8bf a1 = *(const v8bf*)(X0 + ar + (f + 1) * 32);
            accE = MFMA(a0, bfr[f],     accE);
            accO = MFMA(a1, bfr[f + 1], accO);
        }
        bar_vm4();                                         // b2: c1 landed (c2 may fly)
        // 4. phase1: h-lo from H1 (frags 16..31)
        #pragma unroll
        for (int f = 0; f < 16; f += 2) {
            v8bf a0 = *(const v8bf*)(H1 + ar + f * 32);
            v8bf a1 = *(const v8bf*)(H1 + ar + (f + 1) * 32);
            accE = MFMA(a0, bfr[16 + f],     accE);
            accO = MFMA(a1, bfr[16 + f + 1], accO);
        }
        bar_vm0();                                         // b3: c2 landed
        // 5. prefetch next x into X0 (off critical path; drained at b4)
        if (s + 1 < T_) {
            const int tn = dir ? (t - 1) : (t + 1);
            const u16* src = xT + (size_t)tn * B_ * D_ + (size_t)(rh * RPW) * D_;
            #pragma unroll
            for (int r = 0; r < 4; ++r)
                gl_lds(src + (srow + r) * D_ + loff, X0 + (srow + r) * APE);
        }
        // 6. phase2: h-hi from H2 (frags 32..47)
        #pragma unroll
        for (int f = 0; f < 16; f += 2) {
            v8bf a0 = *(const v8bf*)(H2 + ar + f * 32);
            v8bf a1 = *(const v8bf*)(H2 + ar + (f + 1) * 32);
            accE = MFMA(a0, bfr[32 + f],     accE);
            accO = MFMA(a1, bfr[32 + f + 1], accO);
        }
        // 7. write z tile (C layout: col = lane&15, row = quad*4+reg)
        #pragma unroll
        for (int r = 0; r < 4; ++r)
            Cl[(mt * 16 + quad * 4 + r) * CLP + nt * 16 + l15] = accE[r] + accO[r];
        __syncthreads();                                   // b4 (drains x prefetch too)
        // 8. epilogue: gates, c, h (cols: i=0..15, f=16..31, o=32..47, g=48..63)
        float hv;
        {
            const float* C0 = Cl + eb * CLP;
            float zi = C0[ejj]      + bI;
            float zf = C0[16 + ejj] + bF;
            float zo = C0[32 + ejj] + bO;
            float zg = C0[48 + ejj] + bG;
            float iv = sigm(zi), fv = sigm(zf), ov = sigm(zo), gv = tanh_f(zg);
            float cv = fv * cst + iv * gv; cst = cv;
            hv = ov * tanh_f(cv);
            // pack neighbor pair -> one dword coherent write-through per even thread
            unsigned vb = (unsigned)f2bf(hv);
            unsigned ob = (unsigned)__shfl_xor((int)vb, 1);
            if (!(tid & 1)) {
                unsigned hp = vb | (ob << 16);
                __hip_atomic_store(
                    (unsigned*)(hbW + (size_t)eb * H_ + j0 + ejj),
                    hp, __ATOMIC_RELAXED, __HIP_MEMORY_SCOPE_AGENT);
            }
        }
        // 9. publish: b5 drains h stores, then one plain coherent flag store
        __syncthreads();                                   // b5
        if (tid == 0) {
            asm volatile("s_waitcnt vmcnt(0)" ::: "memory");
            __hip_atomic_store(gen + dom * 64 + wid, s + 1, __ATOMIC_RELAXED,
                               __HIP_MEMORY_SCOPE_AGENT);
        }
        // 10. out store AFTER publish — off the critical chain (plain cached, acks at L2)
        out[((size_t)(rh * RPW + eb) * T_ + t) * (2 * H_) + dir * H_ + j0 + ejj] = hv;
    }
}

extern "C" void kernel_launch(void* const* d_in, const int* in_sizes, int n_in,
                              void* d_out, int out_size, void* d_ws, size_t ws_size,
                              hipStream_t stream) {
    const float* xin  = (const float*)d_in[0];
    const float* Wx_f = (const float*)d_in[1];
    const float* Wh_f = (const float*)d_in[2];
    const float* b_f  = (const float*)d_in[3];
    const float* Wx_b = (const float*)d_in[4];
    const float* Wh_b = (const float*)d_in[5];
    const float* b_b  = (const float*)d_in[6];
    float* out = (float*)d_out;

    // workspace layout: hb (8 x 64KB = 512KB) | gen (4KB) | xT (32MB)
    u16* hb  = (u16*)d_ws;
    int* gen = (int*)((char*)d_ws + 524288);
    u16* xT  = (u16*)((char*)d_ws + 528384);

    hipLaunchKernelGGL(prep_kernel, dim3((B_ * T_ * (D_ / 4)) / 256), dim3(256), 0,
                       stream, xin, xT, hb, gen);

    hipFuncSetAttribute(reinterpret_cast<const void*>(scan_kernel),
                        hipFuncAttributeMaxDynamicSharedMemorySize, LDS_TOTAL);

    void* args[] = {(void*)&Wx_f, (void*)&Wh_f, (void*)&b_f,
                    (void*)&Wx_b, (void*)&Wh_b, (void*)&b_b,
                    (void*)&xT, (void*)&hb, (void*)&gen, (void*)&out};
    hipLaunchCooperativeKernel(reinterpret_cast<void*>(scan_kernel),
                               dim3(WGS), dim3(512), args, LDS_TOTAL, stream);
}